// Round 1
// baseline (708.142 us; speedup 1.0000x reference)
//
#include <hip/hip_runtime.h>
#include <hip/hip_bf16.h>
#include <stdint.h>

// MultiheadSelfAttention: B=2, S=4096, D=512, H=8, HD=64
// Pipeline: cvt->bf16 ; fused QKV GEMM (MFMA) ; flash attention (MFMA, online
// softmax) ; output GEMM with split-bf16 (hi/lo) for fp32-grade accuracy.

typedef __attribute__((ext_vector_type(8))) short short8;
typedef __attribute__((ext_vector_type(4))) float floatx4;

#define MFMA(a, b, c) __builtin_amdgcn_mfma_f32_16x16x32_bf16((a), (b), (c), 0, 0, 0)

__device__ __forceinline__ short f2bf(float f) {
    union { float f; uint32_t u; } c; c.f = f;
    uint32_t u = c.u;
    u += 0x7fffu + ((u >> 16) & 1u);   // RNE
    return (short)(u >> 16);
}
__device__ __forceinline__ float bf2f(short s) {
    union { float f; uint32_t u; } c; c.u = ((uint32_t)(uint16_t)s) << 16;
    return c.f;
}

// ---------------------------------------------------------------- converts
__global__ void cvt_bf16(const float* __restrict__ src, short* __restrict__ dst, int n) {
    int i = (blockIdx.x * 256 + threadIdx.x) * 8;
    if (i >= n) return;
    floatx4 v0 = *(const floatx4*)(src + i);
    floatx4 v1 = *(const floatx4*)(src + i + 4);
    short8 o;
    #pragma unroll
    for (int j = 0; j < 4; ++j) { o[j] = f2bf(v0[j]); o[4 + j] = f2bf(v1[j]); }
    *(short8*)(dst + i) = o;
}

__global__ void cvt_split(const float* __restrict__ src, short* __restrict__ hi,
                          short* __restrict__ lo, int n) {
    int i = (blockIdx.x * 256 + threadIdx.x) * 8;
    if (i >= n) return;
    floatx4 v0 = *(const floatx4*)(src + i);
    floatx4 v1 = *(const floatx4*)(src + i + 4);
    short8 h, l;
    #pragma unroll
    for (int j = 0; j < 4; ++j) {
        short hh = f2bf(v0[j]); h[j] = hh; l[j] = f2bf(v0[j] - bf2f(hh));
        short hh1 = f2bf(v1[j]); h[4 + j] = hh1; l[4 + j] = f2bf(v1[j] - bf2f(hh1));
    }
    *(short8*)(hi + i) = h;
    *(short8*)(lo + i) = l;
}

// ---------------------------------------------------------------- QKV GEMM
// q/k/v[m][n] = sum_k X[m][k]*W[n][k] + b[n]; M=8192, K=512, N=512 per weight.
// Grid: (M/64, 1536/64). Epilogue: head split; V stored transposed [bh][hd][s].
__global__ __launch_bounds__(256) void qkv_gemm(
    const short* __restrict__ Xb,
    const short* __restrict__ Wq, const short* __restrict__ Wk, const short* __restrict__ Wv,
    const float* __restrict__ bq, const float* __restrict__ bk, const float* __restrict__ bv,
    short* __restrict__ Qo, short* __restrict__ Ko, short* __restrict__ VTo)
{
    const int lane = threadIdx.x & 63, wave = threadIdx.x >> 6;
    const int col = lane & 15, quad = lane >> 4;
    const int wm = wave & 1, wn = wave >> 1;
    const int m0 = blockIdx.x * 64 + wm * 32;
    const int nblk = blockIdx.y * 64;
    const int which = nblk >> 9;                 // 0=Q,1=K,2=V
    const int nloc = (nblk & 511) + wn * 32;
    const short* W = which == 0 ? Wq : which == 1 ? Wk : Wv;
    const float* bias = which == 0 ? bq : which == 1 ? bk : bv;

    floatx4 acc[2][2] = {};
    const short* a0p = Xb + (size_t)(m0 + col) * 512 + quad * 8;
    const short* b0p = W + (size_t)(nloc + col) * 512 + quad * 8;
    #pragma unroll 4
    for (int k = 0; k < 512; k += 32) {
        short8 a0 = *(const short8*)(a0p + k);
        short8 a1 = *(const short8*)(a0p + 16 * 512 + k);
        short8 b0 = *(const short8*)(b0p + k);
        short8 b1 = *(const short8*)(b0p + 16 * 512 + k);
        acc[0][0] = MFMA(a0, b0, acc[0][0]);
        acc[0][1] = MFMA(a0, b1, acc[0][1]);
        acc[1][0] = MFMA(a1, b0, acc[1][0]);
        acc[1][1] = MFMA(a1, b1, acc[1][1]);
    }
    #pragma unroll
    for (int im = 0; im < 2; ++im)
        #pragma unroll
        for (int in = 0; in < 2; ++in)
            #pragma unroll
            for (int r = 0; r < 4; ++r) {
                int m = m0 + im * 16 + quad * 4 + r;
                int n = nloc + in * 16 + col;
                float v = acc[im][in][r] + bias[n];
                int b = m >> 12, s = m & 4095;
                int h = n >> 6, hd = n & 63;
                int bh = b * 8 + h;
                short bv16 = f2bf(v);
                if (which == 0)      Qo[((size_t)bh * 4096 + s) * 64 + hd] = bv16;
                else if (which == 1) Ko[((size_t)bh * 4096 + s) * 64 + hd] = bv16;
                else                 VTo[((size_t)bh * 64 + hd) * 4096 + s] = bv16;
            }
}

// ---------------------------------------------------------------- flash attn
// Grid (S/64, BH). 4 waves/block, 16 q-rows/wave, 64-key tiles, online softmax.
__global__ __launch_bounds__(256) void flash_attn(
    const short* __restrict__ Q, const short* __restrict__ Kk,
    const short* __restrict__ VT,
    short* __restrict__ Ahi, short* __restrict__ Alo)
{
    __shared__ short Plds[4][16 * 72];            // per-wave P tile, padded stride
    const int lane = threadIdx.x & 63, wave = threadIdx.x >> 6;
    const int col = lane & 15, quad = lane >> 4;
    const int bh = blockIdx.y, b = bh >> 3, h = bh & 7;
    const int q0 = blockIdx.x * 64 + wave * 16;
    const size_t base = (size_t)bh * 4096 * 64;

    const short* qptr = Q + base + (size_t)(q0 + col) * 64 + quad * 8;
    short8 qf0 = *(const short8*)(qptr);
    short8 qf1 = *(const short8*)(qptr + 32);

    floatx4 o[4] = {};
    float m_i[4], l_i[4];
    #pragma unroll
    for (int r = 0; r < 4; ++r) { m_i[r] = -1e30f; l_i[r] = 0.f; }
    short* pw = Plds[wave];

    for (int kk = 0; kk < 4096; kk += 64) {
        floatx4 sa[4];
        #pragma unroll
        for (int nt = 0; nt < 4; ++nt) {
            const short* kptr = Kk + base + (size_t)(kk + nt * 16 + col) * 64 + quad * 8;
            short8 k0 = *(const short8*)(kptr);
            short8 k1 = *(const short8*)(kptr + 32);
            floatx4 z = {0.f, 0.f, 0.f, 0.f};
            z = MFMA(qf0, k0, z);
            sa[nt] = MFMA(qf1, k1, z);
        }
        float rmax[4], rsum[4], newm[4], alpha[4];
        #pragma unroll
        for (int r = 0; r < 4; ++r) {
            float v = fmaxf(fmaxf(sa[0][r], sa[1][r]), fmaxf(sa[2][r], sa[3][r]));
            rmax[r] = v * 0.125f;
        }
        #pragma unroll
        for (int nt = 0; nt < 4; ++nt)
            #pragma unroll
            for (int r = 0; r < 4; ++r) sa[nt][r] *= 0.125f;
        #pragma unroll
        for (int off = 1; off < 16; off <<= 1)
            #pragma unroll
            for (int r = 0; r < 4; ++r)
                rmax[r] = fmaxf(rmax[r], __shfl_xor(rmax[r], off));
        #pragma unroll
        for (int r = 0; r < 4; ++r) {
            newm[r] = fmaxf(m_i[r], rmax[r]);
            alpha[r] = __expf(m_i[r] - newm[r]);
            m_i[r] = newm[r];
            rsum[r] = 0.f;
        }
        #pragma unroll
        for (int nt = 0; nt < 4; ++nt)
            #pragma unroll
            for (int r = 0; r < 4; ++r) {
                float p = __expf(sa[nt][r] - newm[r]);
                rsum[r] += p;
                pw[(quad * 4 + r) * 72 + nt * 16 + col] = f2bf(p);
            }
        #pragma unroll
        for (int off = 1; off < 16; off <<= 1)
            #pragma unroll
            for (int r = 0; r < 4; ++r)
                rsum[r] += __shfl_xor(rsum[r], off);
        #pragma unroll
        for (int r = 0; r < 4; ++r) l_i[r] = l_i[r] * alpha[r] + rsum[r];
        #pragma unroll
        for (int nt = 0; nt < 4; ++nt)
            #pragma unroll
            for (int r = 0; r < 4; ++r) o[nt][r] *= alpha[r];

        __syncthreads();   // P writes visible (per-wave region; orders LDS)
        short8 pf0 = *(const short8*)(pw + col * 72 + quad * 8);
        short8 pf1 = *(const short8*)(pw + col * 72 + 32 + quad * 8);
        __syncthreads();   // reads drained before next iteration's writes

        #pragma unroll
        for (int nt = 0; nt < 4; ++nt) {
            const short* vptr = VT + (size_t)bh * 64 * 4096 + (size_t)(nt * 16 + col) * 4096 + kk + quad * 8;
            short8 v0 = *(const short8*)(vptr);
            short8 v1 = *(const short8*)(vptr + 32);
            o[nt] = MFMA(pf0, v0, o[nt]);
            o[nt] = MFMA(pf1, v1, o[nt]);
        }
    }
    #pragma unroll
    for (int r = 0; r < 4; ++r) {
        float inv = 1.0f / l_i[r];
        int row = q0 + quad * 4 + r;
        size_t rowoff = (size_t)(b * 4096 + row) * 512 + h * 64;
        #pragma unroll
        for (int nt = 0; nt < 4; ++nt) {
            float val = o[nt][r] * inv;
            short hi = f2bf(val);
            short lo = f2bf(val - bf2f(hi));
            Ahi[rowoff + nt * 16 + col] = hi;
            Alo[rowoff + nt * 16 + col] = lo;
        }
    }
}

// ---------------------------------------------------------------- out GEMM
// out[m][n] = sum_k attn[m][k]*Wo[n][k] + bo[n], split-bf16: hh + hl + lh.
__global__ __launch_bounds__(256) void out_gemm(
    const short* __restrict__ Ahi, const short* __restrict__ Alo,
    const short* __restrict__ Whi, const short* __restrict__ Wlo,
    const float* __restrict__ bo, float* __restrict__ Out)
{
    const int lane = threadIdx.x & 63, wave = threadIdx.x >> 6;
    const int col = lane & 15, quad = lane >> 4;
    const int wm = wave & 1, wn = wave >> 1;
    const int m0 = blockIdx.x * 64 + wm * 32;
    const int n0 = blockIdx.y * 64 + wn * 32;
    floatx4 acc[2][2] = {};
    const short* ahp = Ahi + (size_t)(m0 + col) * 512 + quad * 8;
    const short* alp = Alo + (size_t)(m0 + col) * 512 + quad * 8;
    const short* bhp = Whi + (size_t)(n0 + col) * 512 + quad * 8;
    const short* blp = Wlo + (size_t)(n0 + col) * 512 + quad * 8;
    #pragma unroll 2
    for (int k = 0; k < 512; k += 32) {
        short8 ah0 = *(const short8*)(ahp + k);
        short8 ah1 = *(const short8*)(ahp + 16 * 512 + k);
        short8 al0 = *(const short8*)(alp + k);
        short8 al1 = *(const short8*)(alp + 16 * 512 + k);
        short8 bh0 = *(const short8*)(bhp + k);
        short8 bh1 = *(const short8*)(bhp + 16 * 512 + k);
        short8 bl0 = *(const short8*)(blp + k);
        short8 bl1 = *(const short8*)(blp + 16 * 512 + k);
        acc[0][0] = MFMA(ah0, bh0, acc[0][0]);
        acc[0][0] = MFMA(ah0, bl0, acc[0][0]);
        acc[0][0] = MFMA(al0, bh0, acc[0][0]);
        acc[0][1] = MFMA(ah0, bh1, acc[0][1]);
        acc[0][1] = MFMA(ah0, bl1, acc[0][1]);
        acc[0][1] = MFMA(al0, bh1, acc[0][1]);
        acc[1][0] = MFMA(ah1, bh0, acc[1][0]);
        acc[1][0] = MFMA(ah1, bl0, acc[1][0]);
        acc[1][0] = MFMA(al1, bh0, acc[1][0]);
        acc[1][1] = MFMA(ah1, bh1, acc[1][1]);
        acc[1][1] = MFMA(ah1, bl1, acc[1][1]);
        acc[1][1] = MFMA(al1, bh1, acc[1][1]);
    }
    #pragma unroll
    for (int i = 0; i < 2; ++i)
        #pragma unroll
        for (int j = 0; j < 2; ++j)
            #pragma unroll
            for (int r = 0; r < 4; ++r) {
                int m = m0 + i * 16 + quad * 4 + r;
                int n = n0 + j * 16 + col;
                Out[(size_t)m * 512 + n] = acc[i][j][r] + bo[n];
            }
}

// ---------------------------------------------------------------- launcher
extern "C" void kernel_launch(void* const* d_in, const int* in_sizes, int n_in,
                              void* d_out, int out_size, void* d_ws, size_t ws_size,
                              hipStream_t stream) {
    (void)in_sizes; (void)n_in; (void)out_size; (void)ws_size;
    const float* x   = (const float*)d_in[0];
    const float* W_q = (const float*)d_in[1];
    const float* b_q = (const float*)d_in[2];
    const float* W_k = (const float*)d_in[3];
    const float* b_k = (const float*)d_in[4];
    const float* W_v = (const float*)d_in[5];
    const float* b_v = (const float*)d_in[6];
    const float* W_o = (const float*)d_in[7];
    const float* b_o = (const float*)d_in[8];
    float* out = (float*)d_out;
    char* ws = (char*)d_ws;

    short* Xb   = (short*)(ws + 0);          // 8192*512*2  = 8,388,608
    short* Wqb  = (short*)(ws + 8388608);    // 512*512*2   =   524,288
    short* Wkb  = (short*)(ws + 8912896);
    short* Wvb  = (short*)(ws + 9437184);
    short* Wohi = (short*)(ws + 9961472);
    short* Wolo = (short*)(ws + 10485760);
    short* Qb   = (short*)(ws + 11010048);   // [16][4096][64] = 8 MB
    short* Kb   = (short*)(ws + 19398656);
    short* VTb  = (short*)(ws + 27787264);   // [16][64][4096]
    short* Ahi  = (short*)(ws + 36175872);   // [8192][512]
    short* Alo  = (short*)(ws + 44564480);   // end 52,953,088 bytes

    cvt_bf16<<<dim3(2048), dim3(256), 0, stream>>>(x, Xb, 4194304);
    cvt_bf16<<<dim3(128), dim3(256), 0, stream>>>(W_q, Wqb, 262144);
    cvt_bf16<<<dim3(128), dim3(256), 0, stream>>>(W_k, Wkb, 262144);
    cvt_bf16<<<dim3(128), dim3(256), 0, stream>>>(W_v, Wvb, 262144);
    cvt_split<<<dim3(128), dim3(256), 0, stream>>>(W_o, Wohi, Wolo, 262144);
    qkv_gemm<<<dim3(128, 24), dim3(256), 0, stream>>>(Xb, Wqb, Wkb, Wvb, b_q, b_k, b_v, Qb, Kb, VTb);
    flash_attn<<<dim3(64, 16), dim3(256), 0, stream>>>(Qb, Kb, VTb, Ahi, Alo);
    out_gemm<<<dim3(128, 8), dim3(256), 0, stream>>>(Ahi, Alo, Wohi, Wolo, b_o, out);
}

// Round 2
// 685.851 us; speedup vs baseline: 1.0325x; 1.0325x over previous
//
#include <hip/hip_runtime.h>
#include <hip/hip_bf16.h>
#include <stdint.h>

// MultiheadSelfAttention: B=2, S=4096, D=512, H=8, HD=64
// v2: flash attention computes S^T (swapped MFMA operands) -> per-lane softmax
// rows, 2-shfl reductions, packed b64 LDS P-repack, NO barriers (wave-private),
// exp2 domain (log2e folded into Q scale).

typedef __attribute__((ext_vector_type(8))) short short8;
typedef __attribute__((ext_vector_type(4))) float floatx4;

#define MFMA(a, b, c) __builtin_amdgcn_mfma_f32_16x16x32_bf16((a), (b), (c), 0, 0, 0)

__device__ __forceinline__ short f2bf(float f) {
    union { float f; uint32_t u; } c; c.f = f;
    uint32_t u = c.u;
    u += 0x7fffu + ((u >> 16) & 1u);   // RNE
    return (short)(u >> 16);
}
__device__ __forceinline__ float bf2f(short s) {
    union { float f; uint32_t u; } c; c.u = ((uint32_t)(uint16_t)s) << 16;
    return c.f;
}
__device__ __forceinline__ int pack2(float a, float b) {
    return (int)(uint16_t)f2bf(a) | ((int)(uint16_t)f2bf(b) << 16);
}

// ---------------------------------------------------------------- converts
__global__ void cvt_bf16(const float* __restrict__ src, short* __restrict__ dst, int n) {
    int i = (blockIdx.x * 256 + threadIdx.x) * 8;
    if (i >= n) return;
    floatx4 v0 = *(const floatx4*)(src + i);
    floatx4 v1 = *(const floatx4*)(src + i + 4);
    short8 o;
    #pragma unroll
    for (int j = 0; j < 4; ++j) { o[j] = f2bf(v0[j]); o[4 + j] = f2bf(v1[j]); }
    *(short8*)(dst + i) = o;
}

// three weight matrices (262144 elems each) in one launch
__global__ void cvt3_bf16(const float* __restrict__ s0, const float* __restrict__ s1,
                          const float* __restrict__ s2, short* __restrict__ d0,
                          short* __restrict__ d1, short* __restrict__ d2) {
    int idx = blockIdx.x * 256 + threadIdx.x;
    int which = idx >> 15;                      // 32768 threads * 8 = 262144
    int i = (idx & 32767) * 8;
    const float* src = which == 0 ? s0 : which == 1 ? s1 : s2;
    short* dst = which == 0 ? d0 : which == 1 ? d1 : d2;
    floatx4 v0 = *(const floatx4*)(src + i);
    floatx4 v1 = *(const floatx4*)(src + i + 4);
    short8 o;
    #pragma unroll
    for (int j = 0; j < 4; ++j) { o[j] = f2bf(v0[j]); o[4 + j] = f2bf(v1[j]); }
    *(short8*)(dst + i) = o;
}

__global__ void cvt_split(const float* __restrict__ src, short* __restrict__ hi,
                          short* __restrict__ lo, int n) {
    int i = (blockIdx.x * 256 + threadIdx.x) * 8;
    if (i >= n) return;
    floatx4 v0 = *(const floatx4*)(src + i);
    floatx4 v1 = *(const floatx4*)(src + i + 4);
    short8 h, l;
    #pragma unroll
    for (int j = 0; j < 4; ++j) {
        short hh = f2bf(v0[j]); h[j] = hh; l[j] = f2bf(v0[j] - bf2f(hh));
        short hh1 = f2bf(v1[j]); h[4 + j] = hh1; l[4 + j] = f2bf(v1[j] - bf2f(hh1));
    }
    *(short8*)(hi + i) = h;
    *(short8*)(lo + i) = l;
}

// ---------------------------------------------------------------- QKV GEMM
// q/k/v[m][n] = sum_k X[m][k]*W[n][k] + b[n]; Q gets *0.125*log2(e) folded in.
__global__ __launch_bounds__(256) void qkv_gemm(
    const short* __restrict__ Xb,
    const short* __restrict__ Wq, const short* __restrict__ Wk, const short* __restrict__ Wv,
    const float* __restrict__ bq, const float* __restrict__ bk, const float* __restrict__ bv,
    short* __restrict__ Qo, short* __restrict__ Ko, short* __restrict__ VTo)
{
    const int lane = threadIdx.x & 63, wave = threadIdx.x >> 6;
    const int col = lane & 15, quad = lane >> 4;
    const int wm = wave & 1, wn = wave >> 1;
    const int m0 = blockIdx.x * 64 + wm * 32;
    const int nblk = blockIdx.y * 64;
    const int which = nblk >> 9;                 // 0=Q,1=K,2=V
    const int nloc = (nblk & 511) + wn * 32;
    const short* W = which == 0 ? Wq : which == 1 ? Wk : Wv;
    const float* bias = which == 0 ? bq : which == 1 ? bk : bv;
    const float oscale = which == 0 ? 0.1803368801111204f : 1.0f;  // 0.125*log2e

    floatx4 acc[2][2] = {};
    const short* a0p = Xb + (size_t)(m0 + col) * 512 + quad * 8;
    const short* b0p = W + (size_t)(nloc + col) * 512 + quad * 8;
    #pragma unroll 4
    for (int k = 0; k < 512; k += 32) {
        short8 a0 = *(const short8*)(a0p + k);
        short8 a1 = *(const short8*)(a0p + 16 * 512 + k);
        short8 b0 = *(const short8*)(b0p + k);
        short8 b1 = *(const short8*)(b0p + 16 * 512 + k);
        acc[0][0] = MFMA(a0, b0, acc[0][0]);
        acc[0][1] = MFMA(a0, b1, acc[0][1]);
        acc[1][0] = MFMA(a1, b0, acc[1][0]);
        acc[1][1] = MFMA(a1, b1, acc[1][1]);
    }
    #pragma unroll
    for (int im = 0; im < 2; ++im)
        #pragma unroll
        for (int in = 0; in < 2; ++in)
            #pragma unroll
            for (int r = 0; r < 4; ++r) {
                int m = m0 + im * 16 + quad * 4 + r;
                int n = nloc + in * 16 + col;
                float v = (acc[im][in][r] + bias[n]) * oscale;
                int b = m >> 12, s = m & 4095;
                int h = n >> 6, hd = n & 63;
                int bh = b * 8 + h;
                short bv16 = f2bf(v);
                if (which == 0)      Qo[((size_t)bh * 4096 + s) * 64 + hd] = bv16;
                else if (which == 1) Ko[((size_t)bh * 4096 + s) * 64 + hd] = bv16;
                else                 VTo[((size_t)bh * 64 + hd) * 4096 + s] = bv16;
            }
}

// ---------------------------------------------------------------- flash attn
// Grid (S/64, BH). 4 waves/block, 16 q-rows/wave, 64-key tiles.
// Scores computed TRANSPOSED: sa[nt] C-layout holds S^T[t][q]:
//   lane: q = lane&15 (fixed!), t = kk + nt*16 + quad*4 + r.
// Softmax: in-register over 16 regs + 2 shfl_xor across quads. Wave-private
// LDS repack (no barriers): P[q][t] stride 72, b64 writes / b128 reads.
// PV: O^T = V^T * P^T -> o[mt] C-layout: hd = mt*16+quad*4+r, q = lane&15.
__global__ __launch_bounds__(256) void flash_attn(
    const short* __restrict__ Q, const short* __restrict__ Kk,
    const short* __restrict__ VT,
    short* __restrict__ Ahi, short* __restrict__ Alo)
{
    __shared__ short Plds[4][16 * 72];
    const int lane = threadIdx.x & 63, wave = threadIdx.x >> 6;
    const int col = lane & 15, quad = lane >> 4;
    const int bh = blockIdx.y, b = bh >> 3, h = bh & 7;
    const int q0 = blockIdx.x * 64 + wave * 16;
    const size_t base = (size_t)bh * 4096 * 64;
    const size_t vbase = (size_t)bh * 64 * 4096;

    // Q as B-operand: lane holds n=q0+col, k=hd chunk (pre-scaled by 0.125*log2e)
    const short* qptr = Q + base + (size_t)(q0 + col) * 64 + quad * 8;
    short8 qf0 = *(const short8*)(qptr);
    short8 qf1 = *(const short8*)(qptr + 32);

    floatx4 o[4] = {};
    float m_i = -1e30f, l_i = 0.f;
    short* pw = Plds[wave];

    for (int kk = 0; kk < 4096; kk += 64) {
        // S^T tiles: D = K * Q^T
        floatx4 sa[4];
        #pragma unroll
        for (int nt = 0; nt < 4; ++nt) {
            const short* kptr = Kk + base + (size_t)(kk + nt * 16 + col) * 64 + quad * 8;
            short8 k0 = *(const short8*)(kptr);
            short8 k1 = *(const short8*)(kptr + 32);
            floatx4 z = {0.f, 0.f, 0.f, 0.f};
            z = MFMA(k0, qf0, z);
            sa[nt] = MFMA(k1, qf1, z);
        }
        // row max: 16 in-register values + cross-quad
        float tmax = sa[0][0];
        #pragma unroll
        for (int nt = 0; nt < 4; ++nt)
            #pragma unroll
            for (int r = 0; r < 4; ++r) tmax = fmaxf(tmax, sa[nt][r]);
        tmax = fmaxf(tmax, __shfl_xor(tmax, 16));
        tmax = fmaxf(tmax, __shfl_xor(tmax, 32));
        float newm = fmaxf(m_i, tmax);
        float alpha = exp2f(m_i - newm);
        m_i = newm;
        float rsum = 0.f;
        #pragma unroll
        for (int nt = 0; nt < 4; ++nt) {
            float p0 = exp2f(sa[nt][0] - newm);
            float p1 = exp2f(sa[nt][1] - newm);
            float p2 = exp2f(sa[nt][2] - newm);
            float p3 = exp2f(sa[nt][3] - newm);
            rsum += (p0 + p1) + (p2 + p3);
            int2 pk; pk.x = pack2(p0, p1); pk.y = pack2(p2, p3);
            *(int2*)(pw + col * 72 + nt * 16 + quad * 4) = pk;
        }
        rsum += __shfl_xor(rsum, 16);
        rsum += __shfl_xor(rsum, 32);
        l_i = l_i * alpha + rsum;
        #pragma unroll
        for (int mt = 0; mt < 4; ++mt)
            #pragma unroll
            for (int r = 0; r < 4; ++r) o[mt][r] *= alpha;

        // V loads (independent of LDS) issued before the LDS drain
        short8 v0[4], v1[4];
        #pragma unroll
        for (int mt = 0; mt < 4; ++mt) {
            const short* vptr = VT + vbase + (size_t)(mt * 16 + col) * 4096 + kk + quad * 8;
            v0[mt] = *(const short8*)(vptr);
            v1[mt] = *(const short8*)(vptr + 32);
        }

        asm volatile("s_waitcnt lgkmcnt(0)" ::: "memory");   // cross-lane P visible
        short8 pf0 = *(const short8*)(pw + col * 72 + quad * 8);        // t chunk 0
        short8 pf1 = *(const short8*)(pw + col * 72 + 32 + quad * 8);   // t chunk 1
        asm volatile("" ::: "memory");   // pin reads before next iter's writes

        #pragma unroll
        for (int mt = 0; mt < 4; ++mt) {
            o[mt] = MFMA(v0[mt], pf0, o[mt]);
            o[mt] = MFMA(v1[mt], pf1, o[mt]);
        }
    }
    float inv = 1.0f / l_i;
    size_t rowoff = (size_t)(b * 4096 + q0 + col) * 512 + h * 64;
    #pragma unroll
    for (int mt = 0; mt < 4; ++mt) {
        float v0 = o[mt][0] * inv, v1 = o[mt][1] * inv;
        float v2 = o[mt][2] * inv, v3 = o[mt][3] * inv;
        int2 hi, lo;
        hi.x = pack2(v0, v1); hi.y = pack2(v2, v3);
        lo.x = pack2(v0 - bf2f(f2bf(v0)), v1 - bf2f(f2bf(v1)));
        lo.y = pack2(v2 - bf2f(f2bf(v2)), v3 - bf2f(f2bf(v3)));
        *(int2*)(Ahi + rowoff + mt * 16 + quad * 4) = hi;
        *(int2*)(Alo + rowoff + mt * 16 + quad * 4) = lo;
    }
}

// ---------------------------------------------------------------- out GEMM
// out[m][n] = sum_k attn[m][k]*Wo[n][k] + bo[n], split-bf16: hh + hl + lh.
__global__ __launch_bounds__(256) void out_gemm(
    const short* __restrict__ Ahi, const short* __restrict__ Alo,
    const short* __restrict__ Whi, const short* __restrict__ Wlo,
    const float* __restrict__ bo, float* __restrict__ Out)
{
    const int lane = threadIdx.x & 63, wave = threadIdx.x >> 6;
    const int col = lane & 15, quad = lane >> 4;
    const int wm = wave & 1, wn = wave >> 1;
    const int m0 = blockIdx.x * 64 + wm * 32;
    const int n0 = blockIdx.y * 64 + wn * 32;
    floatx4 acc[2][2] = {};
    const short* ahp = Ahi + (size_t)(m0 + col) * 512 + quad * 8;
    const short* alp = Alo + (size_t)(m0 + col) * 512 + quad * 8;
    const short* bhp = Whi + (size_t)(n0 + col) * 512 + quad * 8;
    const short* blp = Wlo + (size_t)(n0 + col) * 512 + quad * 8;
    #pragma unroll 2
    for (int k = 0; k < 512; k += 32) {
        short8 ah0 = *(const short8*)(ahp + k);
        short8 ah1 = *(const short8*)(ahp + 16 * 512 + k);
        short8 al0 = *(const short8*)(alp + k);
        short8 al1 = *(const short8*)(alp + 16 * 512 + k);
        short8 bh0 = *(const short8*)(bhp + k);
        short8 bh1 = *(const short8*)(bhp + 16 * 512 + k);
        short8 bl0 = *(const short8*)(blp + k);
        short8 bl1 = *(const short8*)(blp + 16 * 512 + k);
        acc[0][0] = MFMA(ah0, bh0, acc[0][0]);
        acc[0][0] = MFMA(ah0, bl0, acc[0][0]);
        acc[0][0] = MFMA(al0, bh0, acc[0][0]);
        acc[0][1] = MFMA(ah0, bh1, acc[0][1]);
        acc[0][1] = MFMA(ah0, bl1, acc[0][1]);
        acc[0][1] = MFMA(al0, bh1, acc[0][1]);
        acc[1][0] = MFMA(ah1, bh0, acc[1][0]);
        acc[1][0] = MFMA(ah1, bl0, acc[1][0]);
        acc[1][0] = MFMA(al1, bh0, acc[1][0]);
        acc[1][1] = MFMA(ah1, bh1, acc[1][1]);
        acc[1][1] = MFMA(ah1, bl1, acc[1][1]);
        acc[1][1] = MFMA(al1, bh1, acc[1][1]);
    }
    #pragma unroll
    for (int i = 0; i < 2; ++i)
        #pragma unroll
        for (int j = 0; j < 2; ++j)
            #pragma unroll
            for (int r = 0; r < 4; ++r) {
                int m = m0 + i * 16 + quad * 4 + r;
                int n = n0 + j * 16 + col;
                Out[(size_t)m * 512 + n] = acc[i][j][r] + bo[n];
            }
}

// ---------------------------------------------------------------- launcher
extern "C" void kernel_launch(void* const* d_in, const int* in_sizes, int n_in,
                              void* d_out, int out_size, void* d_ws, size_t ws_size,
                              hipStream_t stream) {
    (void)in_sizes; (void)n_in; (void)out_size; (void)ws_size;
    const float* x   = (const float*)d_in[0];
    const float* W_q = (const float*)d_in[1];
    const float* b_q = (const float*)d_in[2];
    const float* W_k = (const float*)d_in[3];
    const float* b_k = (const float*)d_in[4];
    const float* W_v = (const float*)d_in[5];
    const float* b_v = (const float*)d_in[6];
    const float* W_o = (const float*)d_in[7];
    const float* b_o = (const float*)d_in[8];
    float* out = (float*)d_out;
    char* ws = (char*)d_ws;

    short* Xb   = (short*)(ws + 0);          // 8192*512*2  = 8,388,608
    short* Wqb  = (short*)(ws + 8388608);    // 512*512*2   =   524,288
    short* Wkb  = (short*)(ws + 8912896);
    short* Wvb  = (short*)(ws + 9437184);
    short* Wohi = (short*)(ws + 9961472);
    short* Wolo = (short*)(ws + 10485760);
    short* Qb   = (short*)(ws + 11010048);   // [16][4096][64] = 8 MB
    short* Kb   = (short*)(ws + 19398656);
    short* VTb  = (short*)(ws + 27787264);   // [16][64][4096]
    short* Ahi  = (short*)(ws + 36175872);   // [8192][512]
    short* Alo  = (short*)(ws + 44564480);   // end 52,953,088 bytes

    cvt_bf16<<<dim3(2048), dim3(256), 0, stream>>>(x, Xb, 4194304);
    cvt3_bf16<<<dim3(384), dim3(256), 0, stream>>>(W_q, W_k, W_v, Wqb, Wkb, Wvb);
    cvt_split<<<dim3(128), dim3(256), 0, stream>>>(W_o, Wohi, Wolo, 262144);
    qkv_gemm<<<dim3(128, 24), dim3(256), 0, stream>>>(Xb, Wqb, Wkb, Wvb, b_q, b_k, b_v, Qb, Kb, VTb);
    flash_attn<<<dim3(64, 16), dim3(256), 0, stream>>>(Qb, Kb, VTb, Ahi, Alo);
    out_gemm<<<dim3(128, 8), dim3(256), 0, stream>>>(Ahi, Alo, Wohi, Wolo, b_o, out);
}